// Round 3
// baseline (811.675 us; speedup 1.0000x reference)
//
#include <hip/hip_runtime.h>
#include <math.h>

// ============================================================================
// FreeConvNetwork: 3 locally-connected conv layers + 2 FC + softmax, N=8192.
// All f32 (CDNA4 has no fp32 MFMA -> vector ALU, ~157 TF ceiling).
//
// Layouts (batch-minor so lane index = n -> coalesced):
//   x   : input  (8192, 27*27)               n-major (as given)
//   h1  : [16][13*13][8192]                  ws @ 0        (88,604,672 B)
//   h2  : [32][6*6][8192]                    ws @ 88604672 (37,748,736 B)
//   h3  : [1024][8192]  f = o*16+y*4+x       ws @ 0        (overlays dead h1)
//   h4  : [512][8192]                        ws @ 33554432 (still inside old h1)
//   out : (8192, 10) row-major
// Peak ws use: 126,353,408 B.
//
// Weight/bias addresses in K2..K5 depend only on blockIdx + loop counters
// -> block-uniform -> compiler emits s_load (SMEM pipe), VMEM stays for
// activations. FMA:VMEM per thread: K2 16:1, K3 32:1, K4 32:1.
//
// K4 occupancy note: float2 + 512 blocks = 2 waves/SIMD (TLP for L2 latency).
// The float4 (32,8) variant is 1 wave/SIMD -> no latency hiding; same L2
// traffic (1 GB either way), so float2 wins on theory.
// ============================================================================

#define NB 8192

// ---------------------------------------------------------------------------
// K1: L1 locally-connected, stride 2, 27x27 -> 13x13, Cin=1, Cout=16.
// Block stages 16 samples into LDS (transpose) so compute reads are from LDS
// and h1 writes are 64B-line coalesced (16 lanes over n).
// LDS row stride 737 (odd) -> bank = (ni*737+p)%32 spreads ni across banks.
__global__ __launch_bounds__(256) void k_lc1(const float* __restrict__ x,
                                             const float* __restrict__ w1,
                                             const float* __restrict__ b1,
                                             float* __restrict__ h1) {
  __shared__ float xs[16 * 737];
  const int tid = threadIdx.x;
  const int n0 = blockIdx.x * 16;
  for (int ni = 0; ni < 16; ++ni) {
    for (int p = tid; p < 729; p += 256) {
      xs[ni * 737 + p] = x[(n0 + ni) * 729 + p];  // coalesced global read
    }
  }
  __syncthreads();
  const int q = tid & 15;   // sample within block
  const int g = tid >> 4;   // position group
  for (int o = 0; o < 16; ++o) {
    for (int pp = g; pp < 169; pp += 16) {
      const int yy = pp / 13, xx = pp - yy * 13;
      float acc = b1[o * 169 + pp];
#pragma unroll
      for (int k = 0; k < 9; ++k) {
        const int ky = k / 3, kx = k % 3;
        const int ip = (2 * yy + ky) * 27 + (2 * xx + kx);
        acc = fmaf(xs[q * 737 + ip], w1[(o * 9 + k) * 169 + pp], acc);
      }
      h1[(o * 169 + pp) * NB + n0 + q] = fmaxf(acc, 0.f);
    }
  }
}

// ---------------------------------------------------------------------------
// K2: L2 locally-connected, stride 2, 13x13x16 -> 6x6x32, K=144 per position.
// grid (36 pos, 16 n-chunks of 512, 2 o-chunks of 16). float2 per thread.
__global__ __launch_bounds__(256) void k_lc2(const float* __restrict__ h1,
                                             const float* __restrict__ w2,
                                             const float* __restrict__ b2,
                                             float* __restrict__ h2) {
  const int pos = blockIdx.x;              // 0..35
  const int yy = pos / 6, xx = pos % 6;
  const int n = blockIdx.y * 512 + threadIdx.x * 2;
  const int o0 = blockIdx.z * 16;
  float2 acc[16];
#pragma unroll
  for (int oi = 0; oi < 16; ++oi) {
    const float b = b2[(o0 + oi) * 36 + pos];
    acc[oi] = make_float2(b, b);
  }
  for (int c = 0; c < 16; ++c) {
    float2 v[9];
#pragma unroll
    for (int k = 0; k < 9; ++k) {
      const int ky = k / 3, kx = k % 3;
      const int ip = (2 * yy + ky) * 13 + (2 * xx + kx);
      v[k] = *reinterpret_cast<const float2*>(&h1[(c * 169 + ip) * NB + n]);
    }
#pragma unroll
    for (int oi = 0; oi < 16; ++oi) {
#pragma unroll
      for (int k = 0; k < 9; ++k) {
        const float w = w2[(((o0 + oi) * 16 + c) * 9 + k) * 36 + pos];  // s_load
        acc[oi].x = fmaf(v[k].x, w, acc[oi].x);
        acc[oi].y = fmaf(v[k].y, w, acc[oi].y);
      }
    }
  }
#pragma unroll
  for (int oi = 0; oi < 16; ++oi) {
    const float2 r = make_float2(fmaxf(acc[oi].x, 0.f), fmaxf(acc[oi].y, 0.f));
    *reinterpret_cast<float2*>(&h2[((o0 + oi) * 36 + pos) * NB + n]) = r;
  }
}

// ---------------------------------------------------------------------------
// K3: L3 locally-connected, stride 1, 6x6x32 -> 4x4x64, K=288 per position.
// grid (16 pos, 16 n-chunks of 512, 4 o-chunks of 16). Writes h3 in the
// flatten order f = o*16 + y*4 + x (matches reshape(n,-1) of (C,H,W)).
__global__ __launch_bounds__(256) void k_lc3(const float* __restrict__ h2,
                                             const float* __restrict__ w3,
                                             const float* __restrict__ b3,
                                             float* __restrict__ h3) {
  const int pos = blockIdx.x;              // 0..15
  const int yy = pos / 4, xx = pos % 4;
  const int n = blockIdx.y * 512 + threadIdx.x * 2;
  const int o0 = blockIdx.z * 16;
  float2 acc[16];
#pragma unroll
  for (int oi = 0; oi < 16; ++oi) {
    const float b = b3[(o0 + oi) * 16 + pos];
    acc[oi] = make_float2(b, b);
  }
  for (int c = 0; c < 32; ++c) {
    float2 v[9];
#pragma unroll
    for (int k = 0; k < 9; ++k) {
      const int ky = k / 3, kx = k % 3;
      const int ip = (yy + ky) * 6 + (xx + kx);
      v[k] = *reinterpret_cast<const float2*>(&h2[(c * 36 + ip) * NB + n]);
    }
#pragma unroll
    for (int oi = 0; oi < 16; ++oi) {
#pragma unroll
      for (int k = 0; k < 9; ++k) {
        const float w = w3[(((o0 + oi) * 32 + c) * 9 + k) * 16 + pos];  // s_load
        acc[oi].x = fmaf(v[k].x, w, acc[oi].x);
        acc[oi].y = fmaf(v[k].y, w, acc[oi].y);
      }
    }
  }
#pragma unroll
  for (int oi = 0; oi < 16; ++oi) {
    const float2 r = make_float2(fmaxf(acc[oi].x, 0.f), fmaxf(acc[oi].y, 0.f));
    *reinterpret_cast<float2*>(&h3[((o0 + oi) * 16 + pos) * NB + n]) = r;
  }
}

// ---------------------------------------------------------------------------
// K4: FC1 (512x1024) + ReLU. GEMM M=512 K=1024 N=8192, batch-minor.
// 1-D grid of 512 with XCD swizzle: logical (j-chunk x of 32, n-chunk y of 16);
// all 32 blocks sharing an n-chunk land on XCD y%8 -> their 2 MB h3 slice is
// L2-resident on that XCD instead of replicated across 8 L2s.
//   b -> xcd = b%8, idx = b/8, x = idx%32, y = xcd + 8*(idx/32)
// float2/thread: 32 FMA per 8B load; 512 blocks = 2 waves/SIMD.
__global__ __launch_bounds__(256) void k_fc1(const float* __restrict__ h3,
                                             const float* __restrict__ W1,
                                             const float* __restrict__ B1,
                                             float* __restrict__ h4) {
  const int b = blockIdx.x;
  const int xcd = b & 7;
  const int idx = b >> 3;
  const int jx = idx & 31;
  const int ny = xcd + 8 * (idx >> 5);
  const int j0 = jx * 16;
  const int n = ny * 512 + threadIdx.x * 2;
  float2 acc[16];
#pragma unroll
  for (int j = 0; j < 16; ++j) {
    const float b0 = B1[j0 + j];
    acc[j] = make_float2(b0, b0);
  }
#pragma unroll 4
  for (int f = 0; f < 1024; ++f) {
    const float2 v = *reinterpret_cast<const float2*>(&h3[f * NB + n]);
#pragma unroll
    for (int j = 0; j < 16; ++j) {
      const float w = W1[(j0 + j) * 1024 + f];  // s_load (dwordx4 across f)
      acc[j].x = fmaf(v.x, w, acc[j].x);
      acc[j].y = fmaf(v.y, w, acc[j].y);
    }
  }
#pragma unroll
  for (int j = 0; j < 16; ++j) {
    const float2 r = make_float2(fmaxf(acc[j].x, 0.f), fmaxf(acc[j].y, 0.f));
    *reinterpret_cast<float2*>(&h4[(j0 + j) * NB + n]) = r;
  }
}

// ---------------------------------------------------------------------------
// K5: FC2 (10x512) + softmax. One thread per sample.
__global__ __launch_bounds__(256) void k_fc2(const float* __restrict__ h4,
                                             const float* __restrict__ W2,
                                             const float* __restrict__ B2,
                                             float* __restrict__ out) {
  const int n = blockIdx.x * 256 + threadIdx.x;
  float acc[10];
#pragma unroll
  for (int c = 0; c < 10; ++c) acc[c] = B2[c];
#pragma unroll 8
  for (int j = 0; j < 512; ++j) {
    const float v = h4[j * NB + n];
#pragma unroll
    for (int c = 0; c < 10; ++c) acc[c] = fmaf(v, W2[c * 512 + j], acc[c]);
  }
  float m = acc[0];
#pragma unroll
  for (int c = 1; c < 10; ++c) m = fmaxf(m, acc[c]);
  float s = 0.f;
#pragma unroll
  for (int c = 0; c < 10; ++c) {
    acc[c] = expf(acc[c] - m);
    s += acc[c];
  }
  const float inv = 1.f / s;
#pragma unroll
  for (int c = 0; c < 10; ++c) out[n * 10 + c] = acc[c] * inv;
}

// ---------------------------------------------------------------------------
extern "C" void kernel_launch(void* const* d_in, const int* in_sizes, int n_in,
                              void* d_out, int out_size, void* d_ws, size_t ws_size,
                              hipStream_t stream) {
  const float* x  = (const float*)d_in[0];
  const float* w1 = (const float*)d_in[1];
  const float* b1 = (const float*)d_in[2];
  const float* w2 = (const float*)d_in[3];
  const float* b2 = (const float*)d_in[4];
  const float* w3 = (const float*)d_in[5];
  const float* b3 = (const float*)d_in[6];
  const float* W1 = (const float*)d_in[7];
  const float* B1 = (const float*)d_in[8];
  const float* W2 = (const float*)d_in[9];
  const float* B2 = (const float*)d_in[10];
  float* outp = (float*)d_out;

  char* ws = (char*)d_ws;
  float* h1 = (float*)(ws + 0);                       // 16*169*8192*4 = 88,604,672
  float* h2 = (float*)(ws + 88604672);                // 32*36*8192*4  = 37,748,736
  float* h3 = (float*)(ws + 0);                       // overlays dead h1: 33,554,432
  float* h4 = (float*)(ws + 33554432);                // 512*8192*4    = 16,777,216

  k_lc1<<<dim3(NB / 16), dim3(256), 0, stream>>>(x, w1, b1, h1);
  k_lc2<<<dim3(36, 16, 2), dim3(256), 0, stream>>>(h1, w2, b2, h2);
  k_lc3<<<dim3(16, 16, 4), dim3(256), 0, stream>>>(h2, w3, b3, h3);
  k_fc1<<<dim3(512), dim3(256), 0, stream>>>(h3, W1, B1, h4);
  k_fc2<<<dim3(NB / 256), dim3(256), 0, stream>>>(h4, W2, B2, outp);
}

// Round 8
// 489.164 us; speedup vs baseline: 1.6593x; 1.6593x over previous
//
#include <hip/hip_runtime.h>
#include <math.h>

// ============================================================================
// FreeConvNetwork: 3 locally-connected conv layers + 2 FC + softmax, N=8192.
// All f32 (CDNA4 has no fp32 MFMA -> vector ALU, ~157 TF ceiling).
//
// Workspace liveness plan (peak 126,353,408 B, proven round 3):
//   h1  : [16][169][8192] f32   ws @ 0          (88,604,672 B)  live K1..K2
//   h2  : [32][36][8192]  f32   ws @ 88,604,672 (37,748,736 B)  live K2..K3
//   h3  : [1024][8192]    f32   ws @ 0          (33,554,432 B)  live K3..K4
//                               (overlays h1 AFTER h1 is dead)
//   h4  : [512][8192]     f32   ws @ 33,554,432 (16,777,216 B)  live K4..K5
//   w3t : [16][32][64][9] f32   ws @ 50,331,648 ( 1,179,648 B)  written AFTER
//                               K2 (h1 dead), read in K3; above h4, below h1 end.
//
// ROUND 3 LESSON (measured): pos-innermost weight layout -> one 64B-line
// scalar s_load per weight -> k_lc3 latency-bound (VALUBusy 10.7%,
// hbm 3.8%, 345us). Fix: contiguous per-(pos,c,o-chunk) weight chunks.
// ROUND 4 LESSON (failed): transposed weights MUST NOT live inside h1's
// region while h1 is live (K1 clobbered them -> absmax 0.9). There is no
// free workspace below 126.35MB during K2 -> K2 stages weights in LDS
// instead; K3 uses w3t written after K2 into dead-h1 space.
// ============================================================================

#define NB 8192

// ---------------------------------------------------------------------------
// T3: w3 (64,32,9,4,4) -> w3t[pos][c][o][k], 294,912 elements.
// MUST run after k_lc2 (writes into dead-h1 region).
__global__ __launch_bounds__(256) void k_tr3(const float* __restrict__ w3,
                                             float* __restrict__ w3t) {
  const int i = blockIdx.x * 256 + threadIdx.x;
  if (i < 16 * 32 * 64 * 9) {
    const int k = i % 9;
    const int t = i / 9;
    const int o = t % 64;
    const int t2 = t / 64;
    const int c = t2 % 32;
    const int pos = t2 / 32;
    w3t[i] = w3[((o * 32 + c) * 9 + k) * 16 + pos];
  }
}

// ---------------------------------------------------------------------------
// K1: L1 locally-connected, stride 2, 27x27 -> 13x13, Cin=1, Cout=16.
__global__ __launch_bounds__(256) void k_lc1(const float* __restrict__ x,
                                             const float* __restrict__ w1,
                                             const float* __restrict__ b1,
                                             float* __restrict__ h1) {
  __shared__ float xs[16 * 737];
  const int tid = threadIdx.x;
  const int n0 = blockIdx.x * 16;
  for (int ni = 0; ni < 16; ++ni) {
    for (int p = tid; p < 729; p += 256) {
      xs[ni * 737 + p] = x[(n0 + ni) * 729 + p];  // coalesced global read
    }
  }
  __syncthreads();
  const int q = tid & 15;   // sample within block
  const int g = tid >> 4;   // position group
  for (int o = 0; o < 16; ++o) {
    for (int pp = g; pp < 169; pp += 16) {
      const int yy = pp / 13, xx = pp - yy * 13;
      float acc = b1[o * 169 + pp];
#pragma unroll
      for (int k = 0; k < 9; ++k) {
        const int ky = k / 3, kx = k % 3;
        const int ip = (2 * yy + ky) * 27 + (2 * xx + kx);
        acc = fmaf(xs[q * 737 + ip], w1[(o * 9 + k) * 169 + pp], acc);
      }
      h1[(o * 169 + pp) * NB + n0 + q] = fmaxf(acc, 0.f);
    }
  }
}

// ---------------------------------------------------------------------------
// K2: L2 locally-connected, stride 2, 13x13x16 -> 6x6x32, K=144 per position.
// grid (36 pos, 16 n-chunks of 512, 2 o-chunks of 16). float2 per thread.
// Weights staged to LDS once per block (2304 floats, [c][oi][12] padded so
// each (c,oi) row is 16B-aligned -> ds_read_b128 broadcast in hot loop).
__global__ __launch_bounds__(256) void k_lc2(const float* __restrict__ h1,
                                             const float* __restrict__ w2,
                                             const float* __restrict__ b2,
                                             float* __restrict__ h2) {
  __shared__ float wsw[16 * 16 * 12];  // 12 KB
  const int pos = blockIdx.x;              // 0..35
  const int yy = pos / 6, xx = pos % 6;
  const int n = blockIdx.y * 512 + threadIdx.x * 2;
  const int o0 = blockIdx.z * 16;
  {  // one (c,oi) pair per thread: 256 threads = 16c * 16oi
    const int c = threadIdx.x >> 4;
    const int oi = threadIdx.x & 15;
    const int o = o0 + oi;
#pragma unroll
    for (int k = 0; k < 9; ++k)
      wsw[(c * 16 + oi) * 12 + k] = w2[((o * 16 + c) * 9 + k) * 36 + pos];
  }
  __syncthreads();
  float2 acc[16];
#pragma unroll
  for (int oi = 0; oi < 16; ++oi) {
    const float b = b2[(o0 + oi) * 36 + pos];
    acc[oi] = make_float2(b, b);
  }
  for (int c = 0; c < 16; ++c) {
    float2 v[9];
#pragma unroll
    for (int k = 0; k < 9; ++k) {
      const int ky = k / 3, kx = k % 3;
      const int ip = (2 * yy + ky) * 13 + (2 * xx + kx);
      v[k] = *reinterpret_cast<const float2*>(&h1[(c * 169 + ip) * NB + n]);
    }
#pragma unroll
    for (int oi = 0; oi < 16; ++oi) {
      const float* wr = &wsw[(c * 16 + oi) * 12];
      const float4 wa = *reinterpret_cast<const float4*>(wr);      // ds_read_b128
      const float4 wb = *reinterpret_cast<const float4*>(wr + 4);  // broadcast
      const float w8 = wr[8];
      acc[oi].x = fmaf(v[0].x, wa.x, acc[oi].x);
      acc[oi].y = fmaf(v[0].y, wa.x, acc[oi].y);
      acc[oi].x = fmaf(v[1].x, wa.y, acc[oi].x);
      acc[oi].y = fmaf(v[1].y, wa.y, acc[oi].y);
      acc[oi].x = fmaf(v[2].x, wa.z, acc[oi].x);
      acc[oi].y = fmaf(v[2].y, wa.z, acc[oi].y);
      acc[oi].x = fmaf(v[3].x, wa.w, acc[oi].x);
      acc[oi].y = fmaf(v[3].y, wa.w, acc[oi].y);
      acc[oi].x = fmaf(v[4].x, wb.x, acc[oi].x);
      acc[oi].y = fmaf(v[4].y, wb.x, acc[oi].y);
      acc[oi].x = fmaf(v[5].x, wb.y, acc[oi].x);
      acc[oi].y = fmaf(v[5].y, wb.y, acc[oi].y);
      acc[oi].x = fmaf(v[6].x, wb.z, acc[oi].x);
      acc[oi].y = fmaf(v[6].y, wb.z, acc[oi].y);
      acc[oi].x = fmaf(v[7].x, wb.w, acc[oi].x);
      acc[oi].y = fmaf(v[7].y, wb.w, acc[oi].y);
      acc[oi].x = fmaf(v[8].x, w8, acc[oi].x);
      acc[oi].y = fmaf(v[8].y, w8, acc[oi].y);
    }
  }
#pragma unroll
  for (int oi = 0; oi < 16; ++oi) {
    const float2 r = make_float2(fmaxf(acc[oi].x, 0.f), fmaxf(acc[oi].y, 0.f));
    *reinterpret_cast<float2*>(&h2[((o0 + oi) * 36 + pos) * NB + n]) = r;
  }
}

// ---------------------------------------------------------------------------
// K3: L3 locally-connected, stride 1, 6x6x32 -> 4x4x64, K=288 per position.
// grid (16 pos, 16 n-chunks of 512, 4 o-chunks of 16). Writes h3 in the
// flatten order f = o*16 + y*4 + x (matches reshape(n,-1) of (C,H,W)).
// Weights from w3t: per (pos,c,o-chunk) a contiguous 144-float block ->
// wide s_load on the SMEM pipe.
__global__ __launch_bounds__(256) void k_lc3(const float* __restrict__ h2,
                                             const float* __restrict__ w3t,
                                             const float* __restrict__ b3,
                                             float* __restrict__ h3) {
  const int pos = blockIdx.x;              // 0..15
  const int yy = pos / 4, xx = pos % 4;
  const int n = blockIdx.y * 512 + threadIdx.x * 2;
  const int o0 = blockIdx.z * 16;
  float2 acc[16];
#pragma unroll
  for (int oi = 0; oi < 16; ++oi) {
    const float b = b3[(o0 + oi) * 16 + pos];
    acc[oi] = make_float2(b, b);
  }
  for (int c = 0; c < 32; ++c) {
    float2 v[9];
#pragma unroll
    for (int k = 0; k < 9; ++k) {
      const int ky = k / 3, kx = k % 3;
      const int ip = (yy + ky) * 6 + (xx + kx);
      v[k] = *reinterpret_cast<const float2*>(&h2[(c * 36 + ip) * NB + n]);
    }
    const float* __restrict__ wc = w3t + ((pos * 32 + c) * 64 + o0) * 9;
#pragma unroll
    for (int oi = 0; oi < 16; ++oi) {
#pragma unroll
      for (int k = 0; k < 9; ++k) {
        const float w = wc[oi * 9 + k];  // contiguous -> wide s_load
        acc[oi].x = fmaf(v[k].x, w, acc[oi].x);
        acc[oi].y = fmaf(v[k].y, w, acc[oi].y);
      }
    }
  }
#pragma unroll
  for (int oi = 0; oi < 16; ++oi) {
    const float2 r = make_float2(fmaxf(acc[oi].x, 0.f), fmaxf(acc[oi].y, 0.f));
    *reinterpret_cast<float2*>(&h3[((o0 + oi) * 16 + pos) * NB + n]) = r;
  }
}

// ---------------------------------------------------------------------------
// K4: FC1 (512x1024) + ReLU. GEMM M=512 K=1024 N=8192, batch-minor.
// W1 contiguous along f -> wide s_load natively. XCD swizzle; 2 waves/SIMD.
__global__ __launch_bounds__(256) void k_fc1(const float* __restrict__ h3,
                                             const float* __restrict__ W1,
                                             const float* __restrict__ B1,
                                             float* __restrict__ h4) {
  const int b = blockIdx.x;
  const int xcd = b & 7;
  const int idx = b >> 3;
  const int jx = idx & 31;
  const int ny = xcd + 8 * (idx >> 5);
  const int j0 = jx * 16;
  const int n = ny * 512 + threadIdx.x * 2;
  float2 acc[16];
#pragma unroll
  for (int j = 0; j < 16; ++j) {
    const float b0 = B1[j0 + j];
    acc[j] = make_float2(b0, b0);
  }
#pragma unroll 4
  for (int f = 0; f < 1024; ++f) {
    const float2 v = *reinterpret_cast<const float2*>(&h3[f * NB + n]);
#pragma unroll
    for (int j = 0; j < 16; ++j) {
      const float w = W1[(j0 + j) * 1024 + f];
      acc[j].x = fmaf(v.x, w, acc[j].x);
      acc[j].y = fmaf(v.y, w, acc[j].y);
    }
  }
#pragma unroll
  for (int j = 0; j < 16; ++j) {
    const float2 r = make_float2(fmaxf(acc[j].x, 0.f), fmaxf(acc[j].y, 0.f));
    *reinterpret_cast<float2*>(&h4[(j0 + j) * NB + n]) = r;
  }
}

// ---------------------------------------------------------------------------
// K5: FC2 (10x512) + softmax. One thread per sample.
__global__ __launch_bounds__(256) void k_fc2(const float* __restrict__ h4,
                                             const float* __restrict__ W2,
                                             const float* __restrict__ B2,
                                             float* __restrict__ out) {
  const int n = blockIdx.x * 256 + threadIdx.x;
  float acc[10];
#pragma unroll
  for (int c = 0; c < 10; ++c) acc[c] = B2[c];
#pragma unroll 8
  for (int j = 0; j < 512; ++j) {
    const float v = h4[j * NB + n];
#pragma unroll
    for (int c = 0; c < 10; ++c) acc[c] = fmaf(v, W2[c * 512 + j], acc[c]);
  }
  float m = acc[0];
#pragma unroll
  for (int c = 1; c < 10; ++c) m = fmaxf(m, acc[c]);
  float s = 0.f;
#pragma unroll
  for (int c = 0; c < 10; ++c) {
    acc[c] = expf(acc[c] - m);
    s += acc[c];
  }
  const float inv = 1.f / s;
#pragma unroll
  for (int c = 0; c < 10; ++c) out[n * 10 + c] = acc[c] * inv;
}

// ---------------------------------------------------------------------------
extern "C" void kernel_launch(void* const* d_in, const int* in_sizes, int n_in,
                              void* d_out, int out_size, void* d_ws, size_t ws_size,
                              hipStream_t stream) {
  const float* x  = (const float*)d_in[0];
  const float* w1 = (const float*)d_in[1];
  const float* b1 = (const float*)d_in[2];
  const float* w2 = (const float*)d_in[3];
  const float* b2 = (const float*)d_in[4];
  const float* w3 = (const float*)d_in[5];
  const float* b3 = (const float*)d_in[6];
  const float* W1 = (const float*)d_in[7];
  const float* B1 = (const float*)d_in[8];
  const float* W2 = (const float*)d_in[9];
  const float* B2 = (const float*)d_in[10];
  float* outp = (float*)d_out;

  char* ws = (char*)d_ws;
  float* h1  = (float*)(ws + 0);           // 88,604,672 B, live K1..K2
  float* h2  = (float*)(ws + 88604672);    // 37,748,736 B, live K2..K3
  float* h3  = (float*)(ws + 0);           // 33,554,432 B, live K3..K4 (h1 dead)
  float* h4  = (float*)(ws + 33554432);    // 16,777,216 B, live K4..K5 (h1 dead)
  float* w3t = (float*)(ws + 50331648);    //  1,179,648 B, written AFTER K2
                                           //  (h1 dead there), read in K3 only.

  k_lc1<<<dim3(NB / 16), dim3(256), 0, stream>>>(x, w1, b1, h1);
  k_lc2<<<dim3(36, 16, 2), dim3(256), 0, stream>>>(h1, w2, b2, h2);
  k_tr3<<<dim3(1152), dim3(256), 0, stream>>>(w3, w3t);   // after K2: h1 dead
  k_lc3<<<dim3(16, 16, 4), dim3(256), 0, stream>>>(h2, w3t, b3, h3);
  k_fc1<<<dim3(512), dim3(256), 0, stream>>>(h3, W1, B1, h4);
  k_fc2<<<dim3(NB / 256), dim3(256), 0, stream>>>(h4, W2, B2, outp);
}

// Round 12
// 486.136 us; speedup vs baseline: 1.6696x; 1.0062x over previous
//
#include <hip/hip_runtime.h>
#include <math.h>

// ============================================================================
// FreeConvNetwork: 3 locally-connected conv layers + 2 FC + softmax, N=8192.
// All f32 (CDNA4 has no fp32 MFMA -> vector ALU, ~157 TF ceiling).
//
// Workspace liveness plan (peak 126,353,408 B, proven round 3):
//   h1  : [16][169][8192] f32   ws @ 0          (88,604,672 B)  live K1..K2
//   h2  : [32][36][8192]  f32   ws @ 88,604,672 (37,748,736 B)  live K2..K3
//   h3  : [1024][8192]    f32   ws @ 0          (33,554,432 B)  live K3..K4
//                               (overlays h1 AFTER h1 is dead)
//   h4  : [512][8192]     f32   ws @ 33,554,432 (16,777,216 B)  live K4..K5
//   w3t : [16][32][64][9] f32   ws @ 50,331,648 ( 1,179,648 B)  written AFTER
//                               K2 (h1 dead), read in K3; above h4, below h1 end.
//
// ROUND 3 LESSON (measured): pos-innermost weight layout -> one 64B-line
// scalar s_load per weight -> k_lc3 latency-bound (VALUBusy 10.7%, 345us).
// ROUND 4 LESSON (failed): transposed weights must not alias live h1.
// ROUND 8 LESSON (measured): weight fix worked (k_lc3 out of top-5, total
// 811->489us). k_fc1 now #1 at 155-171us: VALUBusy 42%, hbm 4%, occupancy
// 22% -> latency-bound at my self-imposed 2 waves/SIMD (512 blocks).
// FETCH 32.8MB = h3+W1 read exactly once from HBM (L2/XCD path works).
// Fix: j-chunk 16->8, grid 512->1024 blocks = 4 waves/SIMD (50% occ).
// ============================================================================

#define NB 8192

// ---------------------------------------------------------------------------
// T3: w3 (64,32,9,4,4) -> w3t[pos][c][o][k], 294,912 elements.
// MUST run after k_lc2 (writes into dead-h1 region).
__global__ __launch_bounds__(256) void k_tr3(const float* __restrict__ w3,
                                             float* __restrict__ w3t) {
  const int i = blockIdx.x * 256 + threadIdx.x;
  if (i < 16 * 32 * 64 * 9) {
    const int k = i % 9;
    const int t = i / 9;
    const int o = t % 64;
    const int t2 = t / 64;
    const int c = t2 % 32;
    const int pos = t2 / 32;
    w3t[i] = w3[((o * 32 + c) * 9 + k) * 16 + pos];
  }
}

// ---------------------------------------------------------------------------
// K1: L1 locally-connected, stride 2, 27x27 -> 13x13, Cin=1, Cout=16.
__global__ __launch_bounds__(256) void k_lc1(const float* __restrict__ x,
                                             const float* __restrict__ w1,
                                             const float* __restrict__ b1,
                                             float* __restrict__ h1) {
  __shared__ float xs[16 * 737];
  const int tid = threadIdx.x;
  const int n0 = blockIdx.x * 16;
  for (int ni = 0; ni < 16; ++ni) {
    for (int p = tid; p < 729; p += 256) {
      xs[ni * 737 + p] = x[(n0 + ni) * 729 + p];  // coalesced global read
    }
  }
  __syncthreads();
  const int q = tid & 15;   // sample within block
  const int g = tid >> 4;   // position group
  for (int o = 0; o < 16; ++o) {
    for (int pp = g; pp < 169; pp += 16) {
      const int yy = pp / 13, xx = pp - yy * 13;
      float acc = b1[o * 169 + pp];
#pragma unroll
      for (int k = 0; k < 9; ++k) {
        const int ky = k / 3, kx = k % 3;
        const int ip = (2 * yy + ky) * 27 + (2 * xx + kx);
        acc = fmaf(xs[q * 737 + ip], w1[(o * 9 + k) * 169 + pp], acc);
      }
      h1[(o * 169 + pp) * NB + n0 + q] = fmaxf(acc, 0.f);
    }
  }
}

// ---------------------------------------------------------------------------
// K2: L2 locally-connected, stride 2, 13x13x16 -> 6x6x32, K=144 per position.
// grid (36 pos, 16 n-chunks of 512, 2 o-chunks of 16). float2 per thread.
// Weights staged to LDS once per block (2304 floats, [c][oi][12] padded so
// each (c,oi) row is 16B-aligned -> ds_read_b128 broadcast in hot loop).
__global__ __launch_bounds__(256) void k_lc2(const float* __restrict__ h1,
                                             const float* __restrict__ w2,
                                             const float* __restrict__ b2,
                                             float* __restrict__ h2) {
  __shared__ float wsw[16 * 16 * 12];  // 12 KB
  const int pos = blockIdx.x;              // 0..35
  const int yy = pos / 6, xx = pos % 6;
  const int n = blockIdx.y * 512 + threadIdx.x * 2;
  const int o0 = blockIdx.z * 16;
  {  // one (c,oi) pair per thread: 256 threads = 16c * 16oi
    const int c = threadIdx.x >> 4;
    const int oi = threadIdx.x & 15;
    const int o = o0 + oi;
#pragma unroll
    for (int k = 0; k < 9; ++k)
      wsw[(c * 16 + oi) * 12 + k] = w2[((o * 16 + c) * 9 + k) * 36 + pos];
  }
  __syncthreads();
  float2 acc[16];
#pragma unroll
  for (int oi = 0; oi < 16; ++oi) {
    const float b = b2[(o0 + oi) * 36 + pos];
    acc[oi] = make_float2(b, b);
  }
  for (int c = 0; c < 16; ++c) {
    float2 v[9];
#pragma unroll
    for (int k = 0; k < 9; ++k) {
      const int ky = k / 3, kx = k % 3;
      const int ip = (2 * yy + ky) * 13 + (2 * xx + kx);
      v[k] = *reinterpret_cast<const float2*>(&h1[(c * 169 + ip) * NB + n]);
    }
#pragma unroll
    for (int oi = 0; oi < 16; ++oi) {
      const float* wr = &wsw[(c * 16 + oi) * 12];
      const float4 wa = *reinterpret_cast<const float4*>(wr);      // ds_read_b128
      const float4 wb = *reinterpret_cast<const float4*>(wr + 4);  // broadcast
      const float w8 = wr[8];
      acc[oi].x = fmaf(v[0].x, wa.x, acc[oi].x);
      acc[oi].y = fmaf(v[0].y, wa.x, acc[oi].y);
      acc[oi].x = fmaf(v[1].x, wa.y, acc[oi].x);
      acc[oi].y = fmaf(v[1].y, wa.y, acc[oi].y);
      acc[oi].x = fmaf(v[2].x, wa.z, acc[oi].x);
      acc[oi].y = fmaf(v[2].y, wa.z, acc[oi].y);
      acc[oi].x = fmaf(v[3].x, wa.w, acc[oi].x);
      acc[oi].y = fmaf(v[3].y, wa.w, acc[oi].y);
      acc[oi].x = fmaf(v[4].x, wb.x, acc[oi].x);
      acc[oi].y = fmaf(v[4].y, wb.x, acc[oi].y);
      acc[oi].x = fmaf(v[5].x, wb.y, acc[oi].x);
      acc[oi].y = fmaf(v[5].y, wb.y, acc[oi].y);
      acc[oi].x = fmaf(v[6].x, wb.z, acc[oi].x);
      acc[oi].y = fmaf(v[6].y, wb.z, acc[oi].y);
      acc[oi].x = fmaf(v[7].x, wb.w, acc[oi].x);
      acc[oi].y = fmaf(v[7].y, wb.w, acc[oi].y);
      acc[oi].x = fmaf(v[8].x, w8, acc[oi].x);
      acc[oi].y = fmaf(v[8].y, w8, acc[oi].y);
    }
  }
#pragma unroll
  for (int oi = 0; oi < 16; ++oi) {
    const float2 r = make_float2(fmaxf(acc[oi].x, 0.f), fmaxf(acc[oi].y, 0.f));
    *reinterpret_cast<float2*>(&h2[((o0 + oi) * 36 + pos) * NB + n]) = r;
  }
}

// ---------------------------------------------------------------------------
// K3: L3 locally-connected, stride 1, 6x6x32 -> 4x4x64, K=288 per position.
// grid (16 pos, 16 n-chunks of 512, 4 o-chunks of 16). Writes h3 in the
// flatten order f = o*16 + y*4 + x (matches reshape(n,-1) of (C,H,W)).
// Weights from w3t: per (pos,c,o-chunk) a contiguous 144-float block ->
// wide s_load on the SMEM pipe.
__global__ __launch_bounds__(256) void k_lc3(const float* __restrict__ h2,
                                             const float* __restrict__ w3t,
                                             const float* __restrict__ b3,
                                             float* __restrict__ h3) {
  const int pos = blockIdx.x;              // 0..15
  const int yy = pos / 4, xx = pos % 4;
  const int n = blockIdx.y * 512 + threadIdx.x * 2;
  const int o0 = blockIdx.z * 16;
  float2 acc[16];
#pragma unroll
  for (int oi = 0; oi < 16; ++oi) {
    const float b = b3[(o0 + oi) * 16 + pos];
    acc[oi] = make_float2(b, b);
  }
  for (int c = 0; c < 32; ++c) {
    float2 v[9];
#pragma unroll
    for (int k = 0; k < 9; ++k) {
      const int ky = k / 3, kx = k % 3;
      const int ip = (yy + ky) * 6 + (xx + kx);
      v[k] = *reinterpret_cast<const float2*>(&h2[(c * 36 + ip) * NB + n]);
    }
    const float* __restrict__ wc = w3t + ((pos * 32 + c) * 64 + o0) * 9;
#pragma unroll
    for (int oi = 0; oi < 16; ++oi) {
#pragma unroll
      for (int k = 0; k < 9; ++k) {
        const float w = wc[oi * 9 + k];  // contiguous -> wide s_load
        acc[oi].x = fmaf(v[k].x, w, acc[oi].x);
        acc[oi].y = fmaf(v[k].y, w, acc[oi].y);
      }
    }
  }
#pragma unroll
  for (int oi = 0; oi < 16; ++oi) {
    const float2 r = make_float2(fmaxf(acc[oi].x, 0.f), fmaxf(acc[oi].y, 0.f));
    *reinterpret_cast<float2*>(&h3[((o0 + oi) * 16 + pos) * NB + n]) = r;
  }
}

// ---------------------------------------------------------------------------
// K4: FC1 (512x1024) + ReLU. GEMM M=512 K=1024 N=8192, batch-minor.
// ROUND 8: j-chunk 8 (was 16), grid 1024 blocks (was 512) = 4 waves/SIMD,
// 50% occupancy — k_fc1 was latency-bound at 22% occ / 42% VALUBusy.
// Extra h3 re-reads (64x vs 32x) are L2-resident (2MB slice per XCD).
// XCD swizzle: 1024 blocks -> xcd=b&7, idx=b>>3 in [0,128):
//   jx = idx & 63 (64 j-chunks of 8), ny = xcd + 8*(idx>>6) (16 n-chunks).
// 64 consecutive same-XCD blocks share one h3 n-slice -> L2-resident.
__global__ __launch_bounds__(256) void k_fc1(const float* __restrict__ h3,
                                             const float* __restrict__ W1,
                                             const float* __restrict__ B1,
                                             float* __restrict__ h4) {
  const int b = blockIdx.x;
  const int xcd = b & 7;
  const int idx = b >> 3;
  const int jx = idx & 63;
  const int ny = xcd + 8 * (idx >> 6);
  const int j0 = jx * 8;
  const int n = ny * 512 + threadIdx.x * 2;
  float2 acc[8];
#pragma unroll
  for (int j = 0; j < 8; ++j) {
    const float b0 = B1[j0 + j];
    acc[j] = make_float2(b0, b0);
  }
#pragma unroll 4
  for (int f = 0; f < 1024; ++f) {
    const float2 v = *reinterpret_cast<const float2*>(&h3[f * NB + n]);
#pragma unroll
    for (int j = 0; j < 8; ++j) {
      const float w = W1[(j0 + j) * 1024 + f];  // s_load_dwordx4 across f
      acc[j].x = fmaf(v.x, w, acc[j].x);
      acc[j].y = fmaf(v.y, w, acc[j].y);
    }
  }
#pragma unroll
  for (int j = 0; j < 8; ++j) {
    const float2 r = make_float2(fmaxf(acc[j].x, 0.f), fmaxf(acc[j].y, 0.f));
    *reinterpret_cast<float2*>(&h4[(j0 + j) * NB + n]) = r;
  }
}

// ---------------------------------------------------------------------------
// K5: FC2 (10x512) + softmax. One thread per sample.
__global__ __launch_bounds__(256) void k_fc2(const float* __restrict__ h4,
                                             const float* __restrict__ W2,
                                             const float* __restrict__ B2,
                                             float* __restrict__ out) {
  const int n = blockIdx.x * 256 + threadIdx.x;
  float acc[10];
#pragma unroll
  for (int c = 0; c < 10; ++c) acc[c] = B2[c];
#pragma unroll 8
  for (int j = 0; j < 512; ++j) {
    const float v = h4[j * NB + n];
#pragma unroll
    for (int c = 0; c < 10; ++c) acc[c] = fmaf(v, W2[c * 512 + j], acc[c]);
  }
  float m = acc[0];
#pragma unroll
  for (int c = 1; c < 10; ++c) m = fmaxf(m, acc[c]);
  float s = 0.f;
#pragma unroll
  for (int c = 0; c < 10; ++c) {
    acc[c] = expf(acc[c] - m);
    s += acc[c];
  }
  const float inv = 1.f / s;
#pragma unroll
  for (int c = 0; c < 10; ++c) out[n * 10 + c] = acc[c] * inv;
}

// ---------------------------------------------------------------------------
extern "C" void kernel_launch(void* const* d_in, const int* in_sizes, int n_in,
                              void* d_out, int out_size, void* d_ws, size_t ws_size,
                              hipStream_t stream) {
  const float* x  = (const float*)d_in[0];
  const float* w1 = (const float*)d_in[1];
  const float* b1 = (const float*)d_in[2];
  const float* w2 = (const float*)d_in[3];
  const float* b2 = (const float*)d_in[4];
  const float* w3 = (const float*)d_in[5];
  const float* b3 = (const float*)d_in[6];
  const float* W1 = (const float*)d_in[7];
  const float* B1 = (const float*)d_in[8];
  const float* W2 = (const float*)d_in[9];
  const float* B2 = (const float*)d_in[10];
  float* outp = (float*)d_out;

  char* ws = (char*)d_ws;
  float* h1  = (float*)(ws + 0);           // 88,604,672 B, live K1..K2
  float* h2  = (float*)(ws + 88604672);    // 37,748,736 B, live K2..K3
  float* h3  = (float*)(ws + 0);           // 33,554,432 B, live K3..K4 (h1 dead)
  float* h4  = (float*)(ws + 33554432);    // 16,777,216 B, live K4..K5 (h1 dead)
  float* w3t = (float*)(ws + 50331648);    //  1,179,648 B, written AFTER K2
                                           //  (h1 dead there), read in K3 only.

  k_lc1<<<dim3(NB / 16), dim3(256), 0, stream>>>(x, w1, b1, h1);
  k_lc2<<<dim3(36, 16, 2), dim3(256), 0, stream>>>(h1, w2, b2, h2);
  k_tr3<<<dim3(1152), dim3(256), 0, stream>>>(w3, w3t);   // after K2: h1 dead
  k_lc3<<<dim3(16, 16, 4), dim3(256), 0, stream>>>(h2, w3t, b3, h3);
  k_fc1<<<dim3(1024), dim3(256), 0, stream>>>(h3, W1, B1, h4);
  k_fc2<<<dim3(NB / 256), dim3(256), 0, stream>>>(h4, W2, B2, outp);
}